// Round 2
// baseline (4118.406 us; speedup 1.0000x reference)
//
#include <hip/hip_runtime.h>
#include <stdint.h>

// GDiffusionModel: encoder (D->NF->D) + 99x {diffuse(threefry noise) + 3-layer gen} + final diffuse.
// B=16384 rows independent; all state+weights in LDS.
// Noise = JAX threefry2x32 PARTITIONABLE scheme (default since jax 0.4.30):
//   bits[n] = w0 ^ w1 of threefry2x32(folded_key, (0, n)), n = flat row-major index.

#define NUM_STEPS 100
#define DD 256
#define HALFB 8192
#define NHALF 2097152u      // 8192*256: counter offset between row r and r+8192

#define THREADS 512
#define PAIRS 32            // row-pairs per block (rows r and r+8192)
#define ZSTR 264            // z row stride (floats): 264%32==8 -> <=2-way bank aliasing (free)
#define WSTR 36             // weight row stride: conflict-free b128 lanes

// LDS float offsets
#define Z_OFF   0
#define W1_OFF  (Z_OFF + 64*ZSTR)        // [256][36]  layer-1 weight
#define W3_OFF  (W1_OFF + 256*WSTR)      // [256][36]  layer-3 weight TRANSPOSED [d][g]
#define W2_OFF  (W3_OFF + 256*WSTR)      // [32][36]
#define AL_OFF  (W2_OFF + 32*WSTR)       // alpha[256]
#define SG_OFF  (AL_OFF + 256)           // sigma[256]
#define B1_OFF  (SG_OFF + 256)           // [32]
#define B2_OFF  (B1_OFF + 32)            // [32]
#define B3_OFF  (B2_OFF + 32)            // [256]
#define LDS_FLOATS (B3_OFF + 256)        // 37312
#define LDS_BYTES  (LDS_FLOATS * 4)      // 149248 (<160KiB, 1 block/CU, 8 waves)

__device__ __forceinline__ uint32_t rotl32(uint32_t v, int n) {
  return (v << n) | (v >> (32 - n));
}

// Threefry-2x32, 20 rounds — matches jax/_src/prng.py exactly.
__device__ __forceinline__ void tf2x32(uint32_t k0, uint32_t k1,
                                       uint32_t& x0, uint32_t& x1) {
  uint32_t k2 = k0 ^ k1 ^ 0x1BD11BDAu;
  x0 += k0; x1 += k1;
#define TFR(r) { x0 += x1; x1 = rotl32(x1,(r)); x1 ^= x0; }
  TFR(13) TFR(15) TFR(26) TFR(6)
  x0 += k1; x1 += k2 + 1u;
  TFR(17) TFR(29) TFR(16) TFR(24)
  x0 += k2; x1 += k0 + 2u;
  TFR(13) TFR(15) TFR(26) TFR(6)
  x0 += k0; x1 += k1 + 3u;
  TFR(17) TFR(29) TFR(16) TFR(24)
  x0 += k1; x1 += k2 + 4u;
  TFR(13) TFR(15) TFR(26) TFR(6)
  x0 += k2; x1 += k0 + 5u;
#undef TFR
}

// partitionable 32-bit draw for flat index n: xor of both words of block (0, n)
__device__ __forceinline__ uint32_t tf_bits(uint32_t k0, uint32_t k1, uint32_t n) {
  uint32_t x0 = 0u, x1 = n;
  tf2x32(k0, k1, x0, x1);
  return x0 ^ x1;
}

// bits -> uniform(nextafter(-1,0),1) -> sqrt(2)*erfinv(u); XLA ErfInv32 constants.
__device__ __forceinline__ float bits_to_normal(uint32_t b) {
  const float MN = -0.99999994039535522461f;   // nextafterf(-1,0)
  float f = __uint_as_float((b >> 9) | 0x3F800000u) - 1.0f;  // [0,1)
  float u = fmaxf(fmaf(f, 2.0f, MN), MN);      // (maxval-minval) rounds to 2.0f in f32
  float x2 = u * u;
  float w = -__logf(1.0f - x2);                // == log1p(-x2) to ~1ulp here
  float ws = w - 2.5f;
  float ps = 2.81022636e-08f;
  ps = fmaf(ps, ws, 3.43273939e-07f);
  ps = fmaf(ps, ws, -3.5233877e-06f);
  ps = fmaf(ps, ws, -4.39150654e-06f);
  ps = fmaf(ps, ws, 0.00021858087f);
  ps = fmaf(ps, ws, -0.00125372503f);
  ps = fmaf(ps, ws, -0.00417768164f);
  ps = fmaf(ps, ws, 0.246640727f);
  ps = fmaf(ps, ws, 1.50140941f);
  float wb = sqrtf(w) - 3.0f;
  float pb = -0.000200214257f;
  pb = fmaf(pb, wb, 0.000100950558f);
  pb = fmaf(pb, wb, 0.00134934322f);
  pb = fmaf(pb, wb, -0.00367342844f);
  pb = fmaf(pb, wb, 0.00573950773f);
  pb = fmaf(pb, wb, -0.0076224613f);
  pb = fmaf(pb, wb, 0.00943887047f);
  pb = fmaf(pb, wb, 1.00167406f);
  pb = fmaf(pb, wb, 2.83297682f);
  float p = (w < 5.0f) ? ps : pb;
  return 1.41421356237309515f * (p * u);
}

__global__ __launch_bounds__(THREADS)
void gdiff_kernel(const float* __restrict__ x,
                  const float* __restrict__ alpha, const float* __restrict__ sigma,
                  const float* __restrict__ ew1, const float* __restrict__ eb1,
                  const float* __restrict__ ew2, const float* __restrict__ eb2,
                  const float* __restrict__ gw1, const float* __restrict__ gb1,
                  const float* __restrict__ gw2, const float* __restrict__ gb2,
                  const float* __restrict__ gw3, const float* __restrict__ gb3,
                  float* __restrict__ out)
{
  extern __shared__ float sm[];
  const int t    = threadIdx.x;
  const int pr   = t >> 4;            // pair 0..31
  const int c    = t & 15;            // lane-in-pair
  const int half = c >> 3;            // 0 = row rA, 1 = row rB
  const int cf   = c & 7;
  const int rA   = blockIdx.x * PAIRS + pr;   // 0..8191
  const int rB   = rA + HALFB;
  const int zrow = (pr + half * 32) * ZSTR;   // this lane's mm row base
  const int zA   = pr * ZSTR;
  const int zB   = (pr + 32) * ZSTR;

  // ---------------- stage x into z-LDS (coalesced) ----------------
  {
    const int zr = t >> 3;            // 0..63
    const int j  = t & 7;
    const int gr = (zr < 32) ? (blockIdx.x * PAIRS + zr)
                             : (blockIdx.x * PAIRS + zr - 32 + HALFB);
    const float4* src = reinterpret_cast<const float4*>(x + (size_t)gr * DD + j * 32);
#pragma unroll
    for (int q = 0; q < 8; ++q) {
      *reinterpret_cast<float4*>(&sm[Z_OFF + zr * ZSTR + j * 32 + q * 4]) = src[q];
    }
  }
  // ---------------- stage encoder weights ----------------
  {
    const int r = t >> 1, hh = t & 1;     // ew1 [256][32] -> W1[256][36]
#pragma unroll
    for (int q = 0; q < 4; ++q) {
      float4 v = *reinterpret_cast<const float4*>(ew1 + r * 32 + hh * 16 + q * 4);
      *reinterpret_cast<float4*>(&sm[W1_OFF + r * WSTR + hh * 16 + q * 4]) = v;
    }
  }
  {
    const int g = t >> 4, dc = t & 15;    // ew2 [32][256] -> W3t[d][g]
#pragma unroll
    for (int q = 0; q < 4; ++q) {
      const int d0 = dc * 16 + q * 4;
      float4 v = *reinterpret_cast<const float4*>(ew2 + g * DD + d0);
      sm[W3_OFF + (d0 + 0) * WSTR + g] = v.x;
      sm[W3_OFF + (d0 + 1) * WSTR + g] = v.y;
      sm[W3_OFF + (d0 + 2) * WSTR + g] = v.z;
      sm[W3_OFF + (d0 + 3) * WSTR + g] = v.w;
    }
  }
  if (t < 256) { sm[AL_OFF + t] = alpha[t]; sm[SG_OFF + t] = sigma[t]; sm[B3_OFF + t] = eb2[t]; }
  if (t < 32)  { sm[B1_OFF + t] = eb1[t]; }
  __syncthreads();

  // ---------------- encoder: z = relu(x@ew1+eb1)@ew2 + eb2 ----------------
  {
    float4 h = *reinterpret_cast<const float4*>(&sm[B1_OFF + 4 * cf]);
#pragma unroll 4
    for (int d = 0; d < DD; d += 4) {
      float4 zv = *reinterpret_cast<const float4*>(&sm[Z_OFF + zrow + d]);
      float4 w0 = *reinterpret_cast<const float4*>(&sm[W1_OFF + (d + 0) * WSTR + 4 * cf]);
      float4 w1 = *reinterpret_cast<const float4*>(&sm[W1_OFF + (d + 1) * WSTR + 4 * cf]);
      float4 w2 = *reinterpret_cast<const float4*>(&sm[W1_OFF + (d + 2) * WSTR + 4 * cf]);
      float4 w3 = *reinterpret_cast<const float4*>(&sm[W1_OFF + (d + 3) * WSTR + 4 * cf]);
      h.x = fmaf(zv.x, w0.x, h.x); h.y = fmaf(zv.x, w0.y, h.y);
      h.z = fmaf(zv.x, w0.z, h.z); h.w = fmaf(zv.x, w0.w, h.w);
      h.x = fmaf(zv.y, w1.x, h.x); h.y = fmaf(zv.y, w1.y, h.y);
      h.z = fmaf(zv.y, w1.z, h.z); h.w = fmaf(zv.y, w1.w, h.w);
      h.x = fmaf(zv.z, w2.x, h.x); h.y = fmaf(zv.z, w2.y, h.y);
      h.z = fmaf(zv.z, w2.z, h.z); h.w = fmaf(zv.z, w2.w, h.w);
      h.x = fmaf(zv.w, w3.x, h.x); h.y = fmaf(zv.w, w3.y, h.y);
      h.z = fmaf(zv.w, w3.z, h.z); h.w = fmaf(zv.w, w3.w, h.w);
    }
    h.x = fmaxf(h.x, 0.f); h.y = fmaxf(h.y, 0.f);
    h.z = fmaxf(h.z, 0.f); h.w = fmaxf(h.w, 0.f);
    float h1all[32];
#pragma unroll
    for (int src = 0; src < 8; ++src) {
      h1all[4 * src + 0] = __shfl(h.x, src, 8);
      h1all[4 * src + 1] = __shfl(h.y, src, 8);
      h1all[4 * src + 2] = __shfl(h.z, src, 8);
      h1all[4 * src + 3] = __shfl(h.w, src, 8);
    }
#pragma unroll 2
    for (int k = 0; k < 32; ++k) {       // layer 2, NO relu
      const int d = cf + 8 * k;
      float a0 = sm[B3_OFF + d], a1 = 0.f;
#pragma unroll
      for (int m = 0; m < 8; ++m) {
        float4 wv = *reinterpret_cast<const float4*>(&sm[W3_OFF + d * WSTR + 4 * m]);
        a0 = fmaf(h1all[4 * m + 0], wv.x, a0);
        a1 = fmaf(h1all[4 * m + 1], wv.y, a1);
        a0 = fmaf(h1all[4 * m + 2], wv.z, a0);
        a1 = fmaf(h1all[4 * m + 3], wv.w, a1);
      }
      sm[Z_OFF + zrow + d] = a0 + a1;
    }
  }
  __syncthreads();

  // ---------------- stage generator weights (reuse buffers) ----------------
  {
    const int r = t >> 1, hh = t & 1;
#pragma unroll
    for (int q = 0; q < 4; ++q) {
      float4 v = *reinterpret_cast<const float4*>(gw1 + r * 32 + hh * 16 + q * 4);
      *reinterpret_cast<float4*>(&sm[W1_OFF + r * WSTR + hh * 16 + q * 4]) = v;
    }
  }
  {
    const int g = t >> 4, dc = t & 15;
#pragma unroll
    for (int q = 0; q < 4; ++q) {
      const int d0 = dc * 16 + q * 4;
      float4 v = *reinterpret_cast<const float4*>(gw3 + g * DD + d0);
      sm[W3_OFF + (d0 + 0) * WSTR + g] = v.x;
      sm[W3_OFF + (d0 + 1) * WSTR + g] = v.y;
      sm[W3_OFF + (d0 + 2) * WSTR + g] = v.z;
      sm[W3_OFF + (d0 + 3) * WSTR + g] = v.w;
    }
  }
  if (t < 256) {
    sm[B3_OFF + t] = gb3[t];
    if (t < 32) { sm[B1_OFF + t] = gb1[t]; sm[B2_OFF + t] = gb2[t]; }
    const int r = t >> 3, s8 = t & 7;     // gw2 [32][32] -> [32][36]
    float4 v = *reinterpret_cast<const float4*>(gw2 + r * 32 + s8 * 4);
    *reinterpret_cast<float4*>(&sm[W2_OFF + r * WSTR + s8 * 4]) = v;
  }
  __syncthreads();

  const uint32_t jbase = (uint32_t)rA * 256u + (uint32_t)c;

  // ---------------- 99 steps: diffuse(i) + generator ----------------
#pragma unroll 1
  for (int i = NUM_STEPS - 1; i >= 1; --i) {
    const float tt = (float)i / 100.0f;
    uint32_t c0 = 0u, c1 = (uint32_t)i;
    tf2x32(0u, 42u, c0, c1);              // folded key for step i

    // diffuse: z = z*exp(-0.5*alpha*t) + exp(0.5*sigma*t)*noise  (both rows per lane)
#pragma unroll 2
    for (int k = 0; k < 16; ++k) {
      const int d = c + 16 * k;
      float al = sm[AL_OFF + d], sg = sm[SG_OFF + d];
      float a = __expf(-0.5f * al * tt);
      float s = __expf(0.5f * sg * tt);
      uint32_t nA = jbase + 16u * (uint32_t)k;
      float vA = bits_to_normal(tf_bits(c0, c1, nA));
      float vB = bits_to_normal(tf_bits(c0, c1, nA + NHALF));
      sm[Z_OFF + zA + d] = sm[Z_OFF + zA + d] * a + s * vA;
      sm[Z_OFF + zB + d] = sm[Z_OFF + zB + d] * a + s * vB;
    }
    __syncthreads();

    // layer 1: h = relu(z @ gw1 + gb1), f-split 4/lane, row-split by half
    float4 h = *reinterpret_cast<const float4*>(&sm[B1_OFF + 4 * cf]);
#pragma unroll 4
    for (int d = 0; d < DD; d += 4) {
      float4 zv = *reinterpret_cast<const float4*>(&sm[Z_OFF + zrow + d]);
      float4 w0 = *reinterpret_cast<const float4*>(&sm[W1_OFF + (d + 0) * WSTR + 4 * cf]);
      float4 w1 = *reinterpret_cast<const float4*>(&sm[W1_OFF + (d + 1) * WSTR + 4 * cf]);
      float4 w2 = *reinterpret_cast<const float4*>(&sm[W1_OFF + (d + 2) * WSTR + 4 * cf]);
      float4 w3 = *reinterpret_cast<const float4*>(&sm[W1_OFF + (d + 3) * WSTR + 4 * cf]);
      h.x = fmaf(zv.x, w0.x, h.x); h.y = fmaf(zv.x, w0.y, h.y);
      h.z = fmaf(zv.x, w0.z, h.z); h.w = fmaf(zv.x, w0.w, h.w);
      h.x = fmaf(zv.y, w1.x, h.x); h.y = fmaf(zv.y, w1.y, h.y);
      h.z = fmaf(zv.y, w1.z, h.z); h.w = fmaf(zv.y, w1.w, h.w);
      h.x = fmaf(zv.z, w2.x, h.x); h.y = fmaf(zv.z, w2.y, h.y);
      h.z = fmaf(zv.z, w2.z, h.z); h.w = fmaf(zv.z, w2.w, h.w);
      h.x = fmaf(zv.w, w3.x, h.x); h.y = fmaf(zv.w, w3.y, h.y);
      h.z = fmaf(zv.w, w3.z, h.z); h.w = fmaf(zv.w, w3.w, h.w);
    }
    h.x = fmaxf(h.x, 0.f); h.y = fmaxf(h.y, 0.f);
    h.z = fmaxf(h.z, 0.f); h.w = fmaxf(h.w, 0.f);
    float h1all[32];
#pragma unroll
    for (int src = 0; src < 8; ++src) {
      h1all[4 * src + 0] = __shfl(h.x, src, 8);
      h1all[4 * src + 1] = __shfl(h.y, src, 8);
      h1all[4 * src + 2] = __shfl(h.z, src, 8);
      h1all[4 * src + 3] = __shfl(h.w, src, 8);
    }

    // layer 2: h2 = relu(h1 @ gw2 + gb2), g-split 4/lane
    float4 g2 = *reinterpret_cast<const float4*>(&sm[B2_OFF + 4 * cf]);
#pragma unroll
    for (int f = 0; f < 32; ++f) {
      float4 wv = *reinterpret_cast<const float4*>(&sm[W2_OFF + f * WSTR + 4 * cf]);
      g2.x = fmaf(h1all[f], wv.x, g2.x); g2.y = fmaf(h1all[f], wv.y, g2.y);
      g2.z = fmaf(h1all[f], wv.z, g2.z); g2.w = fmaf(h1all[f], wv.w, g2.w);
    }
    g2.x = fmaxf(g2.x, 0.f); g2.y = fmaxf(g2.y, 0.f);
    g2.z = fmaxf(g2.z, 0.f); g2.w = fmaxf(g2.w, 0.f);
    float h2all[32];
#pragma unroll
    for (int src = 0; src < 8; ++src) {
      h2all[4 * src + 0] = __shfl(g2.x, src, 8);
      h2all[4 * src + 1] = __shfl(g2.y, src, 8);
      h2all[4 * src + 2] = __shfl(g2.z, src, 8);
      h2all[4 * src + 3] = __shfl(g2.w, src, 8);
    }

    // layer 3: z = relu(h2 @ gw3 + gb3), d-split 32/lane (strided 8)
#pragma unroll 2
    for (int k = 0; k < 32; ++k) {
      const int d = cf + 8 * k;
      float a0 = sm[B3_OFF + d], a1 = 0.f;
#pragma unroll
      for (int m = 0; m < 8; ++m) {
        float4 wv = *reinterpret_cast<const float4*>(&sm[W3_OFF + d * WSTR + 4 * m]);
        a0 = fmaf(h2all[4 * m + 0], wv.x, a0);
        a1 = fmaf(h2all[4 * m + 1], wv.y, a1);
        a0 = fmaf(h2all[4 * m + 2], wv.z, a0);
        a1 = fmaf(h2all[4 * m + 3], wv.w, a1);
      }
      sm[Z_OFF + zrow + d] = fmaxf(a0 + a1, 0.f);
    }
    __syncthreads();
  }

  // ---------------- final diffuse (i=0): a=s=1, write out ----------------
  {
    uint32_t c0 = 0u, c1 = 0u;
    tf2x32(0u, 42u, c0, c1);
#pragma unroll 2
    for (int k = 0; k < 16; ++k) {
      const int d = c + 16 * k;
      uint32_t nA = jbase + 16u * (uint32_t)k;
      out[(size_t)rA * DD + d] = sm[Z_OFF + zA + d] + bits_to_normal(tf_bits(c0, c1, nA));
      out[(size_t)rB * DD + d] = sm[Z_OFF + zB + d] + bits_to_normal(tf_bits(c0, c1, nA + NHALF));
    }
  }
}

extern "C" void kernel_launch(void* const* d_in, const int* in_sizes, int n_in,
                              void* d_out, int out_size, void* d_ws, size_t ws_size,
                              hipStream_t stream) {
  (void)in_sizes; (void)n_in; (void)d_ws; (void)ws_size; (void)out_size;
  const float* x     = (const float*)d_in[0];
  const float* alpha = (const float*)d_in[1];
  const float* sigma = (const float*)d_in[2];
  const float* ew1   = (const float*)d_in[3];
  const float* eb1   = (const float*)d_in[4];
  const float* ew2   = (const float*)d_in[5];
  const float* eb2   = (const float*)d_in[6];
  const float* gw1   = (const float*)d_in[7];
  const float* gb1   = (const float*)d_in[8];
  const float* gw2   = (const float*)d_in[9];
  const float* gb2   = (const float*)d_in[10];
  const float* gw3   = (const float*)d_in[11];
  const float* gb3   = (const float*)d_in[12];
  float* out = (float*)d_out;

  (void)hipFuncSetAttribute((const void*)gdiff_kernel,
                            hipFuncAttributeMaxDynamicSharedMemorySize, LDS_BYTES);

  gdiff_kernel<<<256, THREADS, LDS_BYTES, stream>>>(
      x, alpha, sigma, ew1, eb1, ew2, eb2, gw1, gb1, gw2, gb2, gw3, gb3, out);
}

// Round 3
// 3219.723 us; speedup vs baseline: 1.2791x; 1.2791x over previous
//
#include <hip/hip_runtime.h>
#include <stdint.h>

// GDiffusionModel: encoder (D->NF->D) + 99x {3-layer gen + fused diffuse} + out.
// Noise = JAX threefry2x32 partitionable: bits[n] = w0^w1 of tf(key,(0,n)).
// f32 math via v_pk_fma_f32 pairs; lane owns (row, d = cf+8k); 1 barrier/step.

#define NUM_STEPS 100
#define HALFB 8192
#define THREADS 512
#define ZSTR 264          // z row stride: %32==8 -> benign 2-way aliasing
#define WS 36             // W3/W2/hbuf row stride: decorrelates banks for strided-d reads

#define Z_OFF   0
#define W1_OFF  (Z_OFF + 64*ZSTR)     // [256][32] layer-1 weight (unpadded: broadcast reads)
#define W3_OFF  (W1_OFF + 256*32)     // [256][36] layer-3 weight transposed [d][g]
#define W2_OFF  (W3_OFF + 256*WS)     // [32][36]
#define HB_OFF  (W2_OFF + 32*WS)      // [64][36] h broadcast buffer
#define AE_OFF  (HB_OFF + 64*WS)      // [2][256] a=exp(-.5*alpha*t) double-buffered
#define SE_OFF  (AE_OFF + 512)        // [2][256] s=exp(+.5*sigma*t)
#define B1_OFF  (SE_OFF + 512)        // [32]
#define B2_OFF  (B1_OFF + 32)         // [32]
#define B3_OFF  (B2_OFF + 32)         // [256]
#define LDS_FLOATS (B3_OFF + 256)     // 39104 floats
#define LDS_BYTES  (LDS_FLOATS * 4)   // 156416 B < 160 KiB

static_assert(LDS_BYTES <= 160*1024, "LDS overflow");

typedef float v2f __attribute__((ext_vector_type(2)));
typedef float v4f __attribute__((ext_vector_type(4)));

// acc = s0*s1 + acc (pairs)
#define PKFMA(acc,s0,s1)   asm("v_pk_fma_f32 %0, %1, %2, %0" : "+v"(acc) : "v"(s0), "v"(s1))
// acc = broadcast(s0.lo)*s1 + acc
#define PKFMA_L(acc,s0,s1) asm("v_pk_fma_f32 %0, %1, %2, %0 op_sel:[0,0,0] op_sel_hi:[0,1,1]" : "+v"(acc) : "v"(s0), "v"(s1))
// acc = broadcast(s0.hi)*s1 + acc
#define PKFMA_H(acc,s0,s1) asm("v_pk_fma_f32 %0, %1, %2, %0 op_sel:[1,0,0] op_sel_hi:[1,1,1]" : "+v"(acc) : "v"(s0), "v"(s1))
#define PKMUL(d,a,b)       asm("v_pk_mul_f32 %0, %1, %2" : "=v"(d) : "v"(a), "v"(b))

__device__ __forceinline__ uint32_t rotl32(uint32_t v, int n) {
  return (v << n) | (v >> (32 - n));
}

// Threefry-2x32, 20 rounds — matches jax/_src/prng.py exactly.
__device__ __forceinline__ void tf2x32(uint32_t k0, uint32_t k1,
                                       uint32_t& x0, uint32_t& x1) {
  uint32_t k2 = k0 ^ k1 ^ 0x1BD11BDAu;
  x0 += k0; x1 += k1;
#define TFR(r) { x0 += x1; x1 = rotl32(x1,(r)); x1 ^= x0; }
  TFR(13) TFR(15) TFR(26) TFR(6)
  x0 += k1; x1 += k2 + 1u;
  TFR(17) TFR(29) TFR(16) TFR(24)
  x0 += k2; x1 += k0 + 2u;
  TFR(13) TFR(15) TFR(26) TFR(6)
  x0 += k0; x1 += k1 + 3u;
  TFR(17) TFR(29) TFR(16) TFR(24)
  x0 += k1; x1 += k2 + 4u;
  TFR(13) TFR(15) TFR(26) TFR(6)
  x0 += k2; x1 += k0 + 5u;
#undef TFR
}

__device__ __forceinline__ uint32_t tf_bits(uint32_t k0, uint32_t k1, uint32_t n) {
  uint32_t x0 = 0u, x1 = n;
  tf2x32(k0, k1, x0, x1);
  return x0 ^ x1;
}

// two bit-draws -> two sqrt(2)*erfinv(uniform) normals, pk-vectorized polynomial
__device__ __forceinline__ v2f b2n_pk(uint32_t b0, uint32_t b1) {
  const float MN = -0.99999994039535522461f;   // nextafterf(-1,0)
  v2f f = { __uint_as_float((b0 >> 9) | 0x3F800000u),
            __uint_as_float((b1 >> 9) | 0x3F800000u) };
  v2f fm = f - 1.0f;                            // [0,1)
  v2f u = __builtin_elementwise_fma(fm, (v2f)2.0f, (v2f)MN);
  u = __builtin_elementwise_max(u, (v2f)MN);
  v2f x2 = u * u;
  v2f om = 1.0f - x2;
  v2f w  = { -__logf(om.x), -__logf(om.y) };
  v2f ws = w - 2.5f;
  v2f ps = (v2f)2.81022636e-08f;
  ps = __builtin_elementwise_fma(ps, ws, (v2f)3.43273939e-07f);
  ps = __builtin_elementwise_fma(ps, ws, (v2f)-3.5233877e-06f);
  ps = __builtin_elementwise_fma(ps, ws, (v2f)-4.39150654e-06f);
  ps = __builtin_elementwise_fma(ps, ws, (v2f)0.00021858087f);
  ps = __builtin_elementwise_fma(ps, ws, (v2f)-0.00125372503f);
  ps = __builtin_elementwise_fma(ps, ws, (v2f)-0.00417768164f);
  ps = __builtin_elementwise_fma(ps, ws, (v2f)0.246640727f);
  ps = __builtin_elementwise_fma(ps, ws, (v2f)1.50140941f);
  v2f sq = { sqrtf(w.x), sqrtf(w.y) };
  v2f wb = sq - 3.0f;
  v2f pb = (v2f)-0.000200214257f;
  pb = __builtin_elementwise_fma(pb, wb, (v2f)0.000100950558f);
  pb = __builtin_elementwise_fma(pb, wb, (v2f)0.00134934322f);
  pb = __builtin_elementwise_fma(pb, wb, (v2f)-0.00367342844f);
  pb = __builtin_elementwise_fma(pb, wb, (v2f)0.00573950773f);
  pb = __builtin_elementwise_fma(pb, wb, (v2f)-0.0076224613f);
  pb = __builtin_elementwise_fma(pb, wb, (v2f)0.00943887047f);
  pb = __builtin_elementwise_fma(pb, wb, (v2f)1.00167406f);
  pb = __builtin_elementwise_fma(pb, wb, (v2f)2.83297682f);
  v2f p = { (w.x < 5.0f) ? ps.x : pb.x,
            (w.y < 5.0f) ? ps.y : pb.y };
  return (p * u) * 1.41421356237309515f;
}

__global__ __launch_bounds__(THREADS, 2)
void gdiff_kernel(const float* __restrict__ x,
                  const float* __restrict__ alpha, const float* __restrict__ sigma,
                  const float* __restrict__ ew1, const float* __restrict__ eb1,
                  const float* __restrict__ ew2, const float* __restrict__ eb2,
                  const float* __restrict__ gw1, const float* __restrict__ gb1,
                  const float* __restrict__ gw2, const float* __restrict__ gb2,
                  const float* __restrict__ gw3, const float* __restrict__ gb3,
                  float* __restrict__ out)
{
  extern __shared__ float sm[];
  const int t    = threadIdx.x;
  const int pr   = t >> 4;                 // pair 0..31
  const int c    = t & 15;
  const int half = c >> 3;                 // row half
  const int cf   = c & 7;                  // f-lane 0..7
  const int rid  = pr + (half << 5);       // LDS row 0..63
  const int zrow = rid * ZSTR;
  const uint32_t rowg = (uint32_t)(blockIdx.x * 32 + pr) + (uint32_t)(half * HALFB);
  const uint32_t nb   = rowg * 256u + (uint32_t)cf;

  v4f hq0, hq1, hq2, hq3, hq4, hq5, hq6, hq7;   // broadcast h values (32 floats)

  // ---------- staging helpers ----------
  auto stage_w1 = [&](const float* __restrict__ w) {   // [256][32] -> W1 unpadded
    const int r = t >> 1, hh = t & 1;
#pragma unroll
    for (int q = 0; q < 4; ++q)
      *(v4f*)&sm[W1_OFF + r * 32 + hh * 16 + 4 * q] =
          *(const v4f*)&w[r * 32 + hh * 16 + 4 * q];
  };
  auto stage_w3t = [&](const float* __restrict__ w) {  // [32][256] -> W3t[d][g] stride WS
    const int g = t >> 4, dc = t & 15;
#pragma unroll
    for (int q = 0; q < 4; ++q) {
      const int d0 = dc * 16 + q * 4;
      v4f v = *(const v4f*)&w[g * 256 + d0];
      sm[W3_OFF + (d0 + 0) * WS + g] = v.x;
      sm[W3_OFF + (d0 + 1) * WS + g] = v.y;
      sm[W3_OFF + (d0 + 2) * WS + g] = v.z;
      sm[W3_OFF + (d0 + 3) * WS + g] = v.w;
    }
  };

  // ---------- layers ----------
  auto layer1 = [&](v2f& h01, v2f& h23) {
    v4f bv = *(const v4f*)&sm[B1_OFF + 4 * cf];
    h01 = bv.xy; h23 = bv.zw;
    const float* zr_ = &sm[Z_OFF + zrow];
    const float* wp  = &sm[W1_OFF + 4 * cf];
#pragma unroll 4
    for (int d0 = 0; d0 < 256; d0 += 4) {
      v4f z4 = *(const v4f*)&zr_[d0];
      v4f wa = *(const v4f*)&wp[(d0 + 0) * 32];
      v4f wb = *(const v4f*)&wp[(d0 + 1) * 32];
      v4f wc = *(const v4f*)&wp[(d0 + 2) * 32];
      v4f wd = *(const v4f*)&wp[(d0 + 3) * 32];
      PKFMA_L(h01, z4.xy, wa.xy); PKFMA_L(h23, z4.xy, wa.zw);
      PKFMA_H(h01, z4.xy, wb.xy); PKFMA_H(h23, z4.xy, wb.zw);
      PKFMA_L(h01, z4.zw, wc.xy); PKFMA_L(h23, z4.zw, wc.zw);
      PKFMA_H(h01, z4.zw, wd.xy); PKFMA_H(h23, z4.zw, wd.zw);
    }
  };
  auto hwrite = [&](v2f a, v2f b) {
    v4f hv; hv.xy = a; hv.zw = b;
    *(v4f*)&sm[HB_OFF + rid * WS + 4 * cf] = hv;
  };
  auto hload = [&]() {
    const float* hb = &sm[HB_OFF + rid * WS];
    hq0 = *(const v4f*)&hb[0];  hq1 = *(const v4f*)&hb[4];
    hq2 = *(const v4f*)&hb[8];  hq3 = *(const v4f*)&hb[12];
    hq4 = *(const v4f*)&hb[16]; hq5 = *(const v4f*)&hb[20];
    hq6 = *(const v4f*)&hb[24]; hq7 = *(const v4f*)&hb[28];
  };
  auto layer2 = [&](v2f& g01, v2f& g23) {
    v4f bv = *(const v4f*)&sm[B2_OFF + 4 * cf];
    g01 = bv.xy; g23 = bv.zw;
    const float* w2c = &sm[W2_OFF + 4 * cf];
#define L2M(hq, m) { \
    v4f wA = *(const v4f*)&w2c[(4*(m)+0)*WS]; \
    v4f wB = *(const v4f*)&w2c[(4*(m)+1)*WS]; \
    v4f wC = *(const v4f*)&w2c[(4*(m)+2)*WS]; \
    v4f wD = *(const v4f*)&w2c[(4*(m)+3)*WS]; \
    PKFMA_L(g01, hq.xy, wA.xy); PKFMA_L(g23, hq.xy, wA.zw); \
    PKFMA_H(g01, hq.xy, wB.xy); PKFMA_H(g23, hq.xy, wB.zw); \
    PKFMA_L(g01, hq.zw, wC.xy); PKFMA_L(g23, hq.zw, wC.zw); \
    PKFMA_H(g01, hq.zw, wD.xy); PKFMA_H(g23, hq.zw, wD.zw); }
    L2M(hq0,0) L2M(hq1,1) L2M(hq2,2) L2M(hq3,3)
    L2M(hq4,4) L2M(hq5,5) L2M(hq6,6) L2M(hq7,7)
#undef L2M
  };
  // layer-3 (or encoder layer-2) + fused diffuse(j); writes z to LDS
  auto l3d = [&](uint32_t c0p, uint32_t c1p, const float* ae, const float* se, bool relu) {
    const float* w3b = &sm[W3_OFF];
#pragma unroll 2
    for (int kp = 0; kp < 16; ++kp) {
      const int dlo = cf + 16 * kp;
      const int dhi = dlo + 8;
      v2f acc0 = { sm[B3_OFF + dlo], 0.f };
      v2f acc1 = { sm[B3_OFF + dhi], 0.f };
      const float* wl = &w3b[dlo * WS];
      const float* wh = &w3b[dhi * WS];
#define L3M(hq, off) { \
      v4f wvl = *(const v4f*)&wl[off]; \
      v4f wvh = *(const v4f*)&wh[off]; \
      PKFMA(acc0, hq.xy, wvl.xy); PKFMA(acc0, hq.zw, wvl.zw); \
      PKFMA(acc1, hq.xy, wvh.xy); PKFMA(acc1, hq.zw, wvh.zw); }
      L3M(hq0, 0)  L3M(hq1, 4)  L3M(hq2, 8)  L3M(hq3, 12)
      L3M(hq4, 16) L3M(hq5, 20) L3M(hq6, 24) L3M(hq7, 28)
#undef L3M
      float z0 = acc0.x + acc0.y;
      float z1 = acc1.x + acc1.y;
      if (relu) { z0 = fmaxf(z0, 0.f); z1 = fmaxf(z1, 0.f); }
      const uint32_t n0 = nb + (uint32_t)(16 * kp);
      const uint32_t b0 = tf_bits(c0p, c1p, n0);
      const uint32_t b1 = tf_bits(c0p, c1p, n0 + 8u);
      v2f nrm = b2n_pk(b0, b1);
      v2f a2 = { ae[dlo], ae[dhi] };
      v2f s2 = { se[dlo], se[dhi] };
      v2f z2 = { z0, z1 };
      v2f zd; PKMUL(zd, z2, a2); PKFMA(zd, s2, nrm);
      sm[Z_OFF + zrow + dlo] = zd.x;
      sm[Z_OFF + zrow + dhi] = zd.y;
    }
  };

  // ---------------- stage: x, encoder weights, as-table for j=99 ----------------
  {
    const int zr = t >> 3, jj = t & 7;
    const int gr = (zr < 32) ? (blockIdx.x * 32 + zr)
                             : (blockIdx.x * 32 + zr - 32 + HALFB);
    const v4f* src = (const v4f*)(x + (size_t)gr * 256 + jj * 32);
#pragma unroll
    for (int q = 0; q < 8; ++q)
      *(v4f*)&sm[Z_OFF + zr * ZSTR + jj * 32 + q * 4] = src[q];
  }
  stage_w1(ew1);
  stage_w3t(ew2);
  if (t < 256) sm[B3_OFF + t] = eb2[t];
  if (t < 32)  sm[B1_OFF + t] = eb1[t];
  {
    const float t99 = 99.0f / 100.0f;
    if (t < 256) sm[AE_OFF + 256 + t]       = __expf(-0.5f * alpha[t] * t99);
    else         sm[SE_OFF + 256 + (t-256)] = __expf( 0.5f * sigma[t-256] * t99);
  }
  __syncthreads();

  // ---------------- encoder: L1(+relu) -> L2(no relu) + diffuse(99) ----------------
  {
    v2f h01, h23;
    layer1(h01, h23);
    h01 = __builtin_elementwise_max(h01, (v2f)0.f);
    h23 = __builtin_elementwise_max(h23, (v2f)0.f);
    hwrite(h01, h23);
    hload();
    uint32_t e0 = 0u, e1 = 99u;
    tf2x32(0u, 42u, e0, e1);
    l3d(e0, e1, &sm[AE_OFF + 256], &sm[SE_OFF + 256], false);
  }
  __syncthreads();

  // ---------------- restage generator weights ----------------
  stage_w1(gw1);
  stage_w3t(gw3);
  if (t < 256) {
    sm[B3_OFF + t] = gb3[t];
    if (t < 32) { sm[B1_OFF + t] = gb1[t]; sm[B2_OFF + t] = gb2[t]; }
    const int r = t >> 3, s8 = t & 7;   // gw2 [32][32] -> W2 [32][36]
    *(v4f*)&sm[W2_OFF + r * WS + 4 * s8] = *(const v4f*)&gw2[r * 32 + 4 * s8];
  }
  __syncthreads();

  // ---------------- 99 iterations: L1,L2,L3 + diffuse(j=i-1) ----------------
#pragma unroll 1
  for (int i = 99; i >= 1; --i) {
    const int j = i - 1;
    const float tt = (float)j / 100.0f;
    const int buf = (j & 1) << 8;
    if (t < 256) sm[AE_OFF + buf + t]       = __expf(-0.5f * alpha[t] * tt);
    else         sm[SE_OFF + buf + (t-256)] = __expf( 0.5f * sigma[t-256] * tt);
    __syncthreads();   // the only barrier: as-table ready

    v2f h01, h23;
    layer1(h01, h23);
    h01 = __builtin_elementwise_max(h01, (v2f)0.f);
    h23 = __builtin_elementwise_max(h23, (v2f)0.f);
    hwrite(h01, h23);
    hload();

    v2f g01, g23;
    layer2(g01, g23);
    g01 = __builtin_elementwise_max(g01, (v2f)0.f);
    g23 = __builtin_elementwise_max(g23, (v2f)0.f);
    hwrite(g01, g23);
    hload();

    uint32_t e0 = 0u, e1 = (uint32_t)j;
    tf2x32(0u, 42u, e0, e1);
    l3d(e0, e1, &sm[AE_OFF + buf], &sm[SE_OFF + buf], true);
  }
  __syncthreads();

  // ---------------- coalesced output copy ----------------
  {
    const int zr = t >> 3, jj = t & 7;
    const int gr = (zr < 32) ? (blockIdx.x * 32 + zr)
                             : (blockIdx.x * 32 + zr - 32 + HALFB);
    v4f* dst = (v4f*)(out + (size_t)gr * 256 + jj * 32);
#pragma unroll
    for (int q = 0; q < 8; ++q)
      dst[q] = *(const v4f*)&sm[Z_OFF + zr * ZSTR + jj * 32 + q * 4];
  }
}

extern "C" void kernel_launch(void* const* d_in, const int* in_sizes, int n_in,
                              void* d_out, int out_size, void* d_ws, size_t ws_size,
                              hipStream_t stream) {
  (void)in_sizes; (void)n_in; (void)d_ws; (void)ws_size; (void)out_size;
  const float* x     = (const float*)d_in[0];
  const float* alpha = (const float*)d_in[1];
  const float* sigma = (const float*)d_in[2];
  const float* ew1   = (const float*)d_in[3];
  const float* eb1   = (const float*)d_in[4];
  const float* ew2   = (const float*)d_in[5];
  const float* eb2   = (const float*)d_in[6];
  const float* gw1   = (const float*)d_in[7];
  const float* gb1   = (const float*)d_in[8];
  const float* gw2   = (const float*)d_in[9];
  const float* gb2   = (const float*)d_in[10];
  const float* gw3   = (const float*)d_in[11];
  const float* gb3   = (const float*)d_in[12];
  float* out = (float*)d_out;

  (void)hipFuncSetAttribute((const void*)gdiff_kernel,
                            hipFuncAttributeMaxDynamicSharedMemorySize, LDS_BYTES);

  gdiff_kernel<<<256, THREADS, LDS_BYTES, stream>>>(
      x, alpha, sigma, ew1, eb1, ew2, eb2, gw1, gb1, gw2, gb2, gw3, gb3, out);
}